// Round 12
// baseline (91.665 us; speedup 1.0000x reference)
//
#include <hip/hip_runtime.h>
#include <hip/hip_bf16.h>
#include <math.h>

constexpr int NCAPS = 1152;
constexpr int CIN   = 8;
constexpr int COUT  = 16;
constexpr int BATCH = 128;
constexpr int DCAPS = 10;

// ---------------- Kernel A: u = einsum('bni,dnio->dbno'), bf16 out ----------
// Measured ~13 us (R9 probe) — near write floor. Same work shape as R8 (w quad
// loaded once, reused 16 b's; 512 B contiguous x-loads and u-stores per
// wave-instruction). NEW: block id ≡ b%8 (mod 8) and the thread's 16 b's are
// bg+8*bi, so every u[d,b] byte is produced on XCD b%8 — the same XCD whose
// B-block (id = d*128+b, id%8 = b%8) consumes it. If clean L2 lines survive
// the kernel boundary, B's u-read is local-L2 instead of L3.
__global__ __launch_bounds__(256, 1) void u_kernel(
    const float* __restrict__ x,          // [128, 1152, 8]
    const float* __restrict__ w,          // [10, 1152, 8, 16]
    __hip_bfloat16* __restrict__ u)       // [10, 128, 1152, 16] bf16
{
    const int i   = blockIdx.x;           // 1440 blocks
    const int bg  = i & 7;                // b residue == XCD
    const int k   = i >> 3;               // 0..179
    const int nc4 = k % 18;               // 64-row chunk
    const int d   = k / 18;

    const int t    = threadIdx.x;
    const int wv   = t >> 6;              // wave -> 16-row sub-chunk
    const int lane = t & 63;
    const int oq   = lane & 3;
    const int nl   = lane >> 2;           // 0..15
    const int n    = nc4 * 64 + wv * 16 + nl;

    const float* wr = w + ((size_t)(d * NCAPS + n)) * (CIN * COUT) + oq * 4;
    float4 W[CIN];
    #pragma unroll
    for (int ii = 0; ii < CIN; ++ii)
        W[ii] = *(const float4*)(wr + ii * COUT);

    const float* xp = x + ((size_t)bg * NCAPS + n) * CIN;
    __hip_bfloat16* up = u + ((size_t)(d * BATCH + bg) * NCAPS + n) * COUT + oq * 4;

    #pragma unroll
    for (int bi = 0; bi < 16; ++bi) {     // b = bg + 8*bi
        const float4* xr =
            (const float4*)(xp + (size_t)bi * 8 * NCAPS * CIN);
        float4 xa = xr[0], xc = xr[1];
        float xs[CIN] = {xa.x, xa.y, xa.z, xa.w, xc.x, xc.y, xc.z, xc.w};
        float4 acc = {0.f, 0.f, 0.f, 0.f};
        #pragma unroll
        for (int ii = 0; ii < CIN; ++ii) {
            acc.x = fmaf(xs[ii], W[ii].x, acc.x);
            acc.y = fmaf(xs[ii], W[ii].y, acc.y);
            acc.z = fmaf(xs[ii], W[ii].z, acc.z);
            acc.w = fmaf(xs[ii], W[ii].w, acc.w);
        }
        union { unsigned short us[4]; uint2 v; } pk;
        pk.us[0] = __bfloat16_as_ushort(__float2bfloat16(acc.x));
        pk.us[1] = __bfloat16_as_ushort(__float2bfloat16(acc.y));
        pk.us[2] = __bfloat16_as_ushort(__float2bfloat16(acc.z));
        pk.us[3] = __bfloat16_as_ushort(__float2bfloat16(acc.w));
        *(uint2*)(up + (size_t)bi * 8 * NCAPS * COUT) = pk.v;
    }
}

// ---------------- Kernel B: routing over precomputed u ----------------------
// R12: PASS-FUSED routing. R7-R11 showed B pinned at ~24-27 us across
// packed/unpacked/barrier variants -> composite DS+VALU+mem floor; only
// removing work moves it. The agreement-dot of iter i and the exp-weighting
// of iter i+1 read the same u -> fused into ONE unpack pass:
//   dv = u.v; bb += shfl(dv); e = exp(bb-20); p8 += e*u
// 5 -> 3 passes over u (~430 VALU/thread saved). Double-buffered red/zred
// LDS removes the write-after-read barrier: 5 -> 3 barriers.
// Arithmetic order identical to R11 -> absmax must stay exactly 0.01757812.
constexpr int BNT  = 256;
constexpr int BWAV = BNT / 64;
constexpr int JPT  = 9;               // half-rows per thread: 1152*2/256

__device__ __forceinline__ void unpack8(const uint4 pv, float* f) {
    f[0] = __uint_as_float(pv.x << 16);
    f[1] = __uint_as_float(pv.x & 0xffff0000u);
    f[2] = __uint_as_float(pv.y << 16);
    f[3] = __uint_as_float(pv.y & 0xffff0000u);
    f[4] = __uint_as_float(pv.z << 16);
    f[5] = __uint_as_float(pv.z & 0xffff0000u);
    f[6] = __uint_as_float(pv.w << 16);
    f[7] = __uint_as_float(pv.w & 0xffff0000u);
}

__global__ __launch_bounds__(BNT, 1) void routing_kernel(
    const __hip_bfloat16* __restrict__ u, // [10, 128, 1152, 16] bf16
    float* __restrict__ out)              // [10, 128, 16]
{
    __shared__ float red[2][BWAV][COUT];  // double-buffered per-wave partial s
    __shared__ float zred[2][BWAV];       // double-buffered exp-sum partials

    const int i = blockIdx.x;
    const int d = i >> 7;
    const int b = i & 127;

    const int t    = threadIdx.x;
    const int wave = t >> 6;
    const int lane = t & 63;
    const int oh   = t & 1;               // o-half: 0 -> o 0..7, 1 -> o 8..15
    const int r    = t >> 1;              // 0..127

    const __hip_bfloat16* up =
        u + ((size_t)(d * BATCH + b) * NCAPS) * COUT + oh * 8;

    uint4 upk[JPT];                       // u kept PACKED (36 VGPRs)
    #pragma unroll
    for (int j = 0; j < JPT; ++j)
        upk[j] = *(const uint4*)(up + (size_t)(j * 128 + r) * COUT);

    // ---- pass 0: s0 = sum u (uniform c) ----
    float p8[8] = {0.f,0.f,0.f,0.f,0.f,0.f,0.f,0.f};
    #pragma unroll
    for (int j = 0; j < JPT; ++j) {
        float uf[8]; unpack8(upk[j], uf);
        #pragma unroll
        for (int kk = 0; kk < 8; ++kk) p8[kk] += uf[kk];
    }
    #pragma unroll
    for (int off = 2; off < 64; off <<= 1) {
        #pragma unroll
        for (int kk = 0; kk < 8; ++kk) p8[kk] += __shfl_xor(p8[kk], off);
    }
    if (lane < 2) {
        #pragma unroll
        for (int kk = 0; kk < 8; ++kk) red[0][wave][oh * 8 + kk] = p8[kk];
    }
    __syncthreads();                      // barrier 1

    float vloc[8];
    {
        const float scale = 1.f / (float)NCAPS;
        #pragma unroll
        for (int kk = 0; kk < 8; ++kk) {
            float s = red[0][0][oh * 8 + kk] + red[0][1][oh * 8 + kk]
                    + red[0][2][oh * 8 + kk] + red[0][3][oh * 8 + kk];
            s *= scale;
            vloc[kk] = s * fabsf(s) / (1.f + s * s);
        }
    }

    float bb[JPT];
    #pragma unroll
    for (int j = 0; j < JPT; ++j) bb[j] = 0.f;

    // ---- fused passes: agreement(it-1) + exp-weighted sum(it) ----
    #pragma unroll
    for (int it = 1; it < 3; ++it) {
        const int buf = it & 1;           // it1 -> 1, it2 -> 0
        float q8[8] = {0.f,0.f,0.f,0.f,0.f,0.f,0.f,0.f};
        float z = 0.f;
        #pragma unroll
        for (int j = 0; j < JPT; ++j) {
            float uf[8]; unpack8(upk[j], uf);
            float dv = 0.f;
            #pragma unroll
            for (int kk = 0; kk < 8; ++kk) dv = fmaf(uf[kk], vloc[kk], dv);
            dv += __shfl_xor(dv, 1);      // add the other o-half
            bb[j] += dv;
            float e = __expf(bb[j] - 20.f);   // constant-shift softmax
            z += e;
            #pragma unroll
            for (int kk = 0; kk < 8; ++kk) q8[kk] = fmaf(e, uf[kk], q8[kk]);
        }
        #pragma unroll
        for (int off = 2; off < 64; off <<= 1) {
            #pragma unroll
            for (int kk = 0; kk < 8; ++kk) q8[kk] += __shfl_xor(q8[kk], off);
            z += __shfl_xor(z, off);
        }
        if (lane < 2) {
            #pragma unroll
            for (int kk = 0; kk < 8; ++kk) red[buf][wave][oh * 8 + kk] = q8[kk];
            if (lane == 0) zred[buf][wave] = z;
        }
        __syncthreads();                  // barriers 2,3

        const float Z = zred[buf][0] + zred[buf][1]
                      + zred[buf][2] + zred[buf][3];
        const float scale = 1.f / Z;
        #pragma unroll
        for (int kk = 0; kk < 8; ++kk) {
            float s = red[buf][0][oh * 8 + kk] + red[buf][1][oh * 8 + kk]
                    + red[buf][2][oh * 8 + kk] + red[buf][3][oh * 8 + kk];
            s *= scale;
            vloc[kk] = s * fabsf(s) / (1.f + s * s);
        }
    }

    if (t < 2) {                          // t==oh: write this half's 8 floats
        float* op = out + ((size_t)d * BATCH + b) * COUT + oh * 8;
        ((float4*)op)[0] = make_float4(vloc[0], vloc[1], vloc[2], vloc[3]);
        ((float4*)op)[1] = make_float4(vloc[4], vloc[5], vloc[6], vloc[7]);
    }
}

extern "C" void kernel_launch(void* const* d_in, const int* in_sizes, int n_in,
                              void* d_out, int out_size, void* d_ws, size_t ws_size,
                              hipStream_t stream) {
    const float* x = (const float*)d_in[0];
    const float* w = (const float*)d_in[1];
    float* out = (float*)d_out;
    __hip_bfloat16* u = (__hip_bfloat16*)d_ws;   // 10*128*1152*16*2 B = 47 MB

    u_kernel<<<DCAPS * 18 * 8, 256, 0, stream>>>(x, w, u);
    routing_kernel<<<DCAPS * BATCH, BNT, 0, stream>>>(u, out);
}